// Round 11
// baseline (122.896 us; speedup 1.0000x reference)
//
#include <hip/hip_runtime.h>
#include <hip/hip_bf16.h>
#include <cstdint>

// MultiHeadAttention fused pipeline for MI355X (gfx950).
// Phases: cvt(fp32->bf16, fused) -> QKV GEMM (2-phase dbuf, bias + scatter Q/K/V)
//         -> V transpose (LDS-tiled) -> flash attention (causal, dbuf LDS K/V,
//            128-row q-tiles, swapped-QK + cvt_pk) -> out-proj GEMM (dbuf).

#define DEV __device__ __forceinline__

#define VT_STRIDE 2048  // V^T row stride in elems

using bf16x8 = __attribute__((ext_vector_type(8))) short;
using f32x4  = __attribute__((ext_vector_type(4))) float;

DEV unsigned short f2bf(float f) {
  unsigned u = __builtin_bit_cast(unsigned, f);
  u = (u + 0x7fffu + ((u >> 16) & 1u)) >> 16;  // RNE
  return (unsigned short)u;
}

typedef __attribute__((address_space(1))) unsigned int as1_uint;
typedef __attribute__((address_space(3))) unsigned int as3_uint;

// async global->LDS, 16B per lane. LDS dest must be uniform base + lane*16.
DEV void gload_lds16(const void* g, void* l) {
  __builtin_amdgcn_global_load_lds(
      (as1_uint*)(uintptr_t)g,
      (as3_uint*)(unsigned int)(uintptr_t)l,
      16, 0, 0);
}

// fused fp32->bf16 convert for x | W_qkv | W_out (one launch).
#define N4_X  (4096 * 1024 / 4)
#define N4_WQ (3072 * 1024 / 4)
#define N4_WO (1024 * 1024 / 4)
__global__ __launch_bounds__(256) void cvt_all_k(const float* __restrict__ x,
                                                 const float* __restrict__ wq,
                                                 const float* __restrict__ wo,
                                                 unsigned short* __restrict__ xb,
                                                 unsigned short* __restrict__ wqb,
                                                 unsigned short* __restrict__ wob) {
  int i = blockIdx.x * 256 + threadIdx.x;
  const float* in; unsigned short* out;
  if (i < N4_X)                { in = x;  out = xb; }
  else if (i < N4_X + N4_WQ)   { i -= N4_X;  in = wq; out = wqb; }
  else                         { i -= N4_X + N4_WQ; in = wo; out = wob; }
  float4 v = reinterpret_cast<const float4*>(in)[i];
  ushort4 o;
  o.x = f2bf(v.x); o.y = f2bf(v.y); o.z = f2bf(v.z); o.w = f2bf(v.w);
  reinterpret_cast<ushort4*>(out)[i] = o;
}

// V [bh, s, d] -> V^T [bh, d, s].  64x64 tiles through swizzled LDS,
// coalesced global reads AND writes.
__global__ __launch_bounds__(256) void transpose_v_k(const unsigned short* __restrict__ V,
                                                     unsigned short* __restrict__ Vt) {
  const int bh = blockIdx.x;   // 32
  const int st = blockIdx.y;   // 32 s-tiles of 64
  const int tid = threadIdx.x;
  __shared__ unsigned short T[64 * 64];  // 8 KB
  const unsigned short* src = V + ((size_t)bh * 2048 + st * 64) * 64;  // contiguous 8KB

#pragma unroll
  for (int it = 0; it < 2; ++it) {
    const int c = it * 256 + tid;
    const int L = c * 16;
    const int S = L ^ (((L >> 10) & 7) << 4);
    gload_lds16((const char*)src + S, (char*)T + L);
  }
  __syncthreads();

#pragma unroll
  for (int it = 0; it < 2; ++it) {
    const int c = it * 256 + tid;
    const int d = c >> 3;
    const int s_off = (c & 7) * 8;
    const int xg = (c & 7) << 4;
    bf16x8 pk;
#pragma unroll
    for (int j = 0; j < 8; ++j)
      pk[j] = *(const short*)((const char*)T + (((s_off + j) * 128 + d * 2) ^ xg));
    *(bf16x8*)(Vt + (size_t)(bh * 64 + d) * VT_STRIDE + st * 64 + s_off) = pk;
  }
}

// C[M,N] = A[M,K](bf16) * W[N,K](bf16)^T + bias.
// MODE 0: Cout fp32 [M,N].  MODE 1: scatter to Q/K/V, all [bh, s, d] bf16 (coalesced).
// 128x128 tile, BK=64, 4 waves (2x2), 16x16x32 bf16 MFMA.
// 2-PHASE PIPELINE: double-buffered LDS staged via global_load_lds; per K-step
// {STAGE(next) -> s_waitcnt vmcnt(8) -> s_barrier -> MFMA -> s_barrier}.
// T2 XOR-swizzle via pre-swizzled global source.
template <int MODE, int N, int K>
__global__ __launch_bounds__(256) void gemm_bt(const unsigned short* __restrict__ A,
                                               const unsigned short* __restrict__ W,
                                               const float* __restrict__ bias,
                                               float* __restrict__ Cout,
                                               unsigned short* __restrict__ Qp,
                                               unsigned short* __restrict__ Kp,
                                               unsigned short* __restrict__ Vp) {
  __shared__ unsigned short As[2][128 * 64];
  __shared__ unsigned short Bs[2][128 * 64];
  const int tid = threadIdx.x;
  const int m0 = blockIdx.x * 128;
  const int n0 = blockIdx.y * 128;
  const int w = tid >> 6, lane = tid & 63, g = lane >> 4, lr = lane & 15;
  const int wr = w >> 1, wc = w & 1;
  const int xr = (lr & 7) << 4;

  f32x4 acc[4][4];
#pragma unroll
  for (int i = 0; i < 4; ++i)
#pragma unroll
    for (int j = 0; j < 4; ++j)
#pragma unroll
      for (int r = 0; r < 4; ++r) acc[i][j][r] = 0.f;

#define GSTAGE(buf, kt)                                                                     \
  do {                                                                                      \
    _Pragma("unroll")                                                                       \
    for (int it = 0; it < 4; ++it) {                                                        \
      const int c = it * 256 + tid;                                                         \
      const int row = c >> 3;                                                               \
      const int colb = ((c & 7) * 16) ^ ((row & 7) << 4);                                   \
      gload_lds16((const char*)(A + (size_t)(m0 + row) * K + (kt)) + colb,                  \
                  (char*)As[buf] + c * 16);                                                 \
      gload_lds16((const char*)(W + (size_t)(n0 + row) * K + (kt)) + colb,                  \
                  (char*)Bs[buf] + c * 16);                                                 \
    }                                                                                       \
  } while (0)

  GSTAGE(0, 0);
  int cur = 0;
  const int nsteps = K / 64;
  for (int step = 0; step < nsteps; ++step) {
    if (step + 1 < nsteps) {
      GSTAGE(cur ^ 1, (step + 1) * 64);
      asm volatile("s_waitcnt vmcnt(8)" ::: "memory");  // own tile loads landed; 8 newest in flight
    } else {
      asm volatile("s_waitcnt vmcnt(0)" ::: "memory");
    }
    __builtin_amdgcn_s_barrier();   // all waves' current-tile loads landed
    __builtin_amdgcn_sched_barrier(0);

    const char* AsC = (const char*)As[cur];
    const char* BsC = (const char*)Bs[cur];
    __builtin_amdgcn_s_setprio(1);
#pragma unroll
    for (int ks = 0; ks < 2; ++ks) {
      bf16x8 af[4], bf[4];
#pragma unroll
      for (int mi = 0; mi < 4; ++mi)
        af[mi] = *(const bf16x8*)(AsC +
                   ((((wr * 64 + mi * 16 + lr) * 128) + ks * 64 + g * 16) ^ xr));
#pragma unroll
      for (int ni = 0; ni < 4; ++ni)
        bf[ni] = *(const bf16x8*)(BsC +
                   ((((wc * 64 + ni * 16 + lr) * 128) + ks * 64 + g * 16) ^ xr));
#pragma unroll
      for (int mi = 0; mi < 4; ++mi)
#pragma unroll
        for (int ni = 0; ni < 4; ++ni)
          acc[mi][ni] = __builtin_amdgcn_mfma_f32_16x16x32_bf16(af[mi], bf[ni], acc[mi][ni], 0, 0, 0);
    }
    __builtin_amdgcn_s_setprio(0);

    asm volatile("" ::: "memory");
    __builtin_amdgcn_s_barrier();   // all waves done reading buf[cur]
    __builtin_amdgcn_sched_barrier(0);
    cur ^= 1;
  }
#undef GSTAGE

  if (MODE == 0) {
#pragma unroll
    for (int ni = 0; ni < 4; ++ni) {
      const int col = n0 + wc * 64 + ni * 16 + lr;
      const float bv = bias[col];
#pragma unroll
      for (int mi = 0; mi < 4; ++mi)
#pragma unroll
        for (int r = 0; r < 4; ++r) {
          const int row = m0 + wr * 64 + mi * 16 + g * 4 + r;
          Cout[(size_t)row * N + col] = acc[mi][ni][r] + bv;
        }
    }
  } else {
#pragma unroll
    for (int ni = 0; ni < 4; ++ni) {
      const int col = n0 + wc * 64 + ni * 16 + lr;
      const float bv = bias[col];
      const int which = col >> 10;
      const int h = (col >> 6) & 15;
      const int d = col & 63;
      unsigned short* P = which == 0 ? Qp : which == 1 ? Kp : Vp;
#pragma unroll
      for (int mi = 0; mi < 4; ++mi)
#pragma unroll
        for (int r = 0; r < 4; ++r) {
          const int row = m0 + wr * 64 + mi * 16 + g * 4 + r;
          const int b = row >> 11, s = row & 2047;
          P[(((size_t)(b * 16 + h) * 2048 + s) << 6) + d] = f2bf(acc[mi][ni][r] + bv);
        }
    }
  }
}

// Flash attention, causal. grid (bh=32, 16 tiles of 128 q-rows), 256 thr = 4 waves.
// Wave owns 32 q-rows (2 q-fragments) -> per staged K/V tile, 128 q-rows consume it
// (2x round-9 staging efficiency). K/V 64x64 tiles DOUBLE-BUFFERED in swizzled LDS;
// counted s_waitcnt vmcnt(4) + raw s_barrier keeps next tile in flight across
// compute. Swapped QK^T (mfma(K,Q)); K and V fragments loaded once, reused for
// both q-groups. cvt_pk P-pack; no-max exp2 softmax; per-lane l partials.
// Heavy tiles dispatch first (LPT balance). Mask needed on last TWO kv blocks.
__global__ __launch_bounds__(256) void attn_fwd(const unsigned short* __restrict__ Q,
                                                const unsigned short* __restrict__ Kg,
                                                const unsigned short* __restrict__ Vt,
                                                unsigned short* __restrict__ AO) {
  const int bh = blockIdx.x;            // b*16 + h
  const int ti = 15 - blockIdx.y;       // 128-row q tile, heaviest first
  const int tid = threadIdx.x;
  const int w = tid >> 6, lane = tid & 63, g = lane >> 4, lr = lane & 15;
  const unsigned short* Qp = Q  + (size_t)bh * 2048 * 64;
  const unsigned short* Kp = Kg + (size_t)bh * 2048 * 64;
  const unsigned short* Vp = Vt + (size_t)bh * 64 * VT_STRIDE;
  const int b = bh >> 4, h = bh & 15;

  __shared__ unsigned short Ks[2][64 * 64];  // 16 KB dbuf K
  __shared__ unsigned short Vs[2][64 * 64];  // 16 KB dbuf V^T
  __shared__ unsigned short Pl[4][32 * 64];  // 16 KB per-wave P (32 q-rows x 64 keys)

  const float C = 0.1803368801f;  // 0.125 * log2(e)
  char* Plw = (char*)Pl[w];
  const int xr = (lr & 7) << 4;

  const int L0 = tid * 16,         L1 = (tid + 256) * 16;
  const int G0 = L0 ^ (((L0 >> 7) & 7) << 4);
  const int G1 = L1 ^ (((L1 >> 7) & 7) << 4);

#define STAGE(buf, kvb)                                                                     \
  do {                                                                                      \
    gload_lds16((const char*)Kp + (size_t)(kvb) * 128 + G0, (char*)Ks[buf] + L0);           \
    gload_lds16((const char*)Kp + (size_t)(kvb) * 128 + G1, (char*)Ks[buf] + L1);           \
    gload_lds16((const char*)Vp + (size_t)(G0 >> 7) * (VT_STRIDE * 2) + (size_t)(kvb) * 2 + \
                    (G0 & 127), (char*)Vs[buf] + L0);                                       \
    gload_lds16((const char*)Vp + (size_t)(G1 >> 7) * (VT_STRIDE * 2) + (size_t)(kvb) * 2 + \
                    (G1 & 127), (char*)Vs[buf] + L1);                                       \
  } while (0)

  const int nb = 2 * ti + 2;             // kv blocks of 64 cover rows < 128*ti+128
  const int qrow0 = ti * 128 + w * 32;   // this wave's 32 q-rows (2 groups of 16)

  bf16x8 aq[2][2];                       // [q-group][ks]
#pragma unroll
  for (int qg = 0; qg < 2; ++qg)
#pragma unroll
    for (int ks = 0; ks < 2; ++ks)
      aq[qg][ks] = *(const bf16x8*)(Qp + (size_t)(qrow0 + qg * 16 + lr) * 64 + ks * 32 + g * 8);

  f32x4 o[2][4];                         // [q-group][d-block]
  float lp[2] = {0.f, 0.f};              // per-lane partial row sums (q = lr per group)
#pragma unroll
  for (int qg = 0; qg < 2; ++qg)
#pragma unroll
    for (int db = 0; db < 4; ++db)
#pragma unroll
      for (int r = 0; r < 4; ++r) o[qg][db][r] = 0.f;

  STAGE(0, 0);
  int cur = 0;

  for (int t = 0; t < nb; ++t) {
    const int kvb = t * 64;
    if (t + 1 < nb) {
      STAGE(cur ^ 1, (t + 1) * 64);
      asm volatile("s_waitcnt vmcnt(4)" ::: "memory");  // own tile-t loads landed
    } else {
      asm volatile("s_waitcnt vmcnt(0)" ::: "memory");
    }
    __builtin_amdgcn_s_barrier();        // all waves' tile-t loads landed
    __builtin_amdgcn_sched_barrier(0);

    const char* KsC = (const char*)Ks[cur];
    const char* VsC = (const char*)Vs[cur];

    // ---- QK^T SWAPPED: D[col=q=lr, row=key]; K fragment reused for both qg ----
    f32x4 sc[2][4];
#pragma unroll
    for (int qg = 0; qg < 2; ++qg)
#pragma unroll
      for (int f = 0; f < 4; ++f)
#pragma unroll
        for (int r = 0; r < 4; ++r) sc[qg][f][r] = 0.f;
    __builtin_amdgcn_s_setprio(1);
#pragma unroll
    for (int ks = 0; ks < 2; ++ks)
#pragma unroll
      for (int f = 0; f < 4; ++f) {
        bf16x8 bk = *(const bf16x8*)(KsC + (((f * 16 + lr) * 128 + ks * 64 + g * 16) ^ xr));
#pragma unroll
        for (int qg = 0; qg < 2; ++qg)
          sc[qg][f] = __builtin_amdgcn_mfma_f32_16x16x32_bf16(bk, aq[qg][ks], sc[qg][f], 0, 0, 0);
      }
    __builtin_amdgcn_s_setprio(0);

    // ---- causal mask: last TWO kv blocks may cross the diagonal ----
    if (t >= nb - 2) {
#pragma unroll
      for (int qg = 0; qg < 2; ++qg) {
        const int thr = qrow0 + qg * 16 + lr - kvb - g * 4;
#pragma unroll
        for (int f = 0; f < 4; ++f)
#pragma unroll
          for (int r = 0; r < 4; ++r)
            if (f * 16 + r > thr) sc[qg][f][r] = -INFINITY;
      }
    }

    // ---- no-max softmax + per-lane partial sums ----
#pragma unroll
    for (int qg = 0; qg < 2; ++qg)
#pragma unroll
      for (int f = 0; f < 4; ++f) {
        float p0 = exp2f(sc[qg][f][0] * C);
        float p1 = exp2f(sc[qg][f][1] * C);
        float p2 = exp2f(sc[qg][f][2] * C);
        float p3 = exp2f(sc[qg][f][3] * C);
        sc[qg][f][0] = p0; sc[qg][f][1] = p1; sc[qg][f][2] = p2; sc[qg][f][3] = p3;
        lp[qg] += (p0 + p1) + (p2 + p3);
      }

    // ---- P -> LDS (cvt_pk pairs, one b64 per (qg,f)) ----
#pragma unroll
    for (int qg = 0; qg < 2; ++qg)
#pragma unroll
      for (int f = 0; f < 4; ++f) {
        unsigned w0, w1;
        asm("v_cvt_pk_bf16_f32 %0, %1, %2" : "=v"(w0) : "v"(sc[qg][f][0]), "v"(sc[qg][f][1]));
        asm("v_cvt_pk_bf16_f32 %0, %1, %2" : "=v"(w1) : "v"(sc[qg][f][2]), "v"(sc[qg][f][3]));
        uint2 pk; pk.x = w0; pk.y = w1;
        *(uint2*)(Plw + qg * 2048 + ((lr * 128 + f * 32 + g * 8) ^ xr)) = pk;
      }
    asm volatile("s_waitcnt lgkmcnt(0)" ::: "memory");
    __builtin_amdgcn_sched_barrier(0);

    // ---- PV: V fragment reused for both q-groups ----
    __builtin_amdgcn_s_setprio(1);
#pragma unroll
    for (int ks = 0; ks < 2; ++ks) {
      bf16x8 pa[2];
#pragma unroll
      for (int qg = 0; qg < 2; ++qg)
        pa[qg] = *(const bf16x8*)(Plw + qg * 2048 + ((lr * 128 + ks * 64 + g * 16) ^ xr));
#pragma unroll
      for (int db = 0; db < 4; ++db) {
        bf16x8 bv = *(const bf16x8*)(VsC + (((db * 16 + lr) * 128 + ks * 64 + g * 16) ^ xr));
#pragma unroll
        for (int qg = 0; qg < 2; ++qg)
          o[qg][db] = __builtin_amdgcn_mfma_f32_16x16x32_bf16(pa[qg], bv, o[qg][db], 0, 0, 0);
      }
    }
    __builtin_amdgcn_s_setprio(0);

    asm volatile("" ::: "memory");
    __builtin_amdgcn_s_barrier();        // all waves done reading buf[cur]
    __builtin_amdgcn_sched_barrier(0);
    cur ^= 1;
  }

  // ---- finalize: reduce l across the 4 lane-groups, redistribute, output ----
#pragma unroll
  for (int qg = 0; qg < 2; ++qg) {
    float l = lp[qg];
    l += __shfl_xor(l, 16);
    l += __shfl_xor(l, 32);
    const float inv = 1.0f / l;          // valid for q = qrow0 + qg*16 + lr
#pragma unroll
    for (int r = 0; r < 4; ++r) {
      const float linv = __shfl(inv, g * 4 + r);   // l for q-row g*4+r of this group
      const int row = qrow0 + qg * 16 + g * 4 + r;
#pragma unroll
      for (int db = 0; db < 4; ++db)
        AO[(size_t)(b * 2048 + row) * 1024 + h * 64 + db * 16 + lr] = f2bf(o[qg][db][r] * linv);
    }
  }
#undef STAGE
}

extern "C" void kernel_launch(void* const* d_in, const int* in_sizes, int n_in,
                              void* d_out, int out_size, void* d_ws, size_t ws_size,
                              hipStream_t stream) {
  const float* x     = (const float*)d_in[0];
  const float* W_qkv = (const float*)d_in[1];
  const float* b_qkv = (const float*)d_in[2];
  const float* W_out = (const float*)d_in[3];
  const float* b_out = (const float*)d_in[4];
  float* out = (float*)d_out;

  // workspace layout (48 MB exactly, fully rewritten every call)
  // AOb reuses xb's region: xb dead after QKV GEMM completes (stream-ordered).
  char* ws = (char*)d_ws;
  unsigned short* xb  = (unsigned short*)(ws);                      // 8 MB x bf16 [4096,1024]
  unsigned short* AOb = (unsigned short*)(ws);                      // 8 MB attn out (reuse)
  unsigned short* wqb = (unsigned short*)(ws + ((size_t)8 << 20));  // 6 MB W_qkv bf16
  unsigned short* wob = (unsigned short*)(ws + ((size_t)14 << 20)); // 2 MB W_out bf16
  unsigned short* Qb  = (unsigned short*)(ws + ((size_t)16 << 20)); // 8 MB Q [bh,s,d]
  unsigned short* Kb  = (unsigned short*)(ws + ((size_t)24 << 20)); // 8 MB K [bh,s,d]
  unsigned short* Vb  = (unsigned short*)(ws + ((size_t)32 << 20)); // 8 MB V [bh,s,d]
  unsigned short* Vtb = (unsigned short*)(ws + ((size_t)40 << 20)); // 8 MB V^T [bh,d,s]

  cvt_all_k<<<(N4_X + N4_WQ + N4_WO) / 256, 256, 0, stream>>>(x, W_qkv, W_out, xb, wqb, wob);

  gemm_bt<1, 3072, 1024><<<dim3(32, 24), 256, 0, stream>>>(xb, wqb, b_qkv, nullptr, Qb, Kb, Vb);
  transpose_v_k<<<dim3(32, 32), 256, 0, stream>>>(Vb, Vtb);
  attn_fwd<<<dim3(32, 16), 256, 0, stream>>>(Qb, Kb, Vtb, AOb);
  gemm_bt<0, 1024, 1024><<<dim3(32, 8), 256, 0, stream>>>(AOb, wob, b_out, out, nullptr, nullptr, nullptr);
}

// Round 12
// 113.191 us; speedup vs baseline: 1.0857x; 1.0857x over previous
//
#include <hip/hip_runtime.h>
#include <hip/hip_bf16.h>
#include <cstdint>

// MultiHeadAttention fused pipeline for MI355X (gfx950).
// Phases: cvt(fp32->bf16, fused) -> QKV GEMM (2-phase dbuf, bias + scatter Q/K/V)
//         -> V transpose (LDS-tiled) -> flash attention (causal, 8-wave paired
//            128-row tiles, dbuf LDS K/V, swapped-QK + cvt_pk) -> out-proj GEMM.

#define DEV __device__ __forceinline__

#define VT_STRIDE 2048  // V^T row stride in elems

using bf16x8 = __attribute__((ext_vector_type(8))) short;
using f32x4  = __attribute__((ext_vector_type(4))) float;

DEV unsigned short f2bf(float f) {
  unsigned u = __builtin_bit_cast(unsigned, f);
  u = (u + 0x7fffu + ((u >> 16) & 1u)) >> 16;  // RNE
  return (unsigned short)u;
}

typedef __attribute__((address_space(1))) unsigned int as1_uint;
typedef __attribute__((address_space(3))) unsigned int as3_uint;

// async global->LDS, 16B per lane. LDS dest must be uniform base + lane*16.
DEV void gload_lds16(const void* g, void* l) {
  __builtin_amdgcn_global_load_lds(
      (as1_uint*)(uintptr_t)g,
      (as3_uint*)(unsigned int)(uintptr_t)l,
      16, 0, 0);
}

// fused fp32->bf16 convert for x | W_qkv | W_out (one launch).
#define N4_X  (4096 * 1024 / 4)
#define N4_WQ (3072 * 1024 / 4)
#define N4_WO (1024 * 1024 / 4)
__global__ __launch_bounds__(256) void cvt_all_k(const float* __restrict__ x,
                                                 const float* __restrict__ wq,
                                                 const float* __restrict__ wo,
                                                 unsigned short* __restrict__ xb,
                                                 unsigned short* __restrict__ wqb,
                                                 unsigned short* __restrict__ wob) {
  int i = blockIdx.x * 256 + threadIdx.x;
  const float* in; unsigned short* out;
  if (i < N4_X)                { in = x;  out = xb; }
  else if (i < N4_X + N4_WQ)   { i -= N4_X;  in = wq; out = wqb; }
  else                         { i -= N4_X + N4_WQ; in = wo; out = wob; }
  float4 v = reinterpret_cast<const float4*>(in)[i];
  ushort4 o;
  o.x = f2bf(v.x); o.y = f2bf(v.y); o.z = f2bf(v.z); o.w = f2bf(v.w);
  reinterpret_cast<ushort4*>(out)[i] = o;
}

// V [bh, s, d] -> V^T [bh, d, s].  64x64 tiles through swizzled LDS,
// coalesced global reads AND writes.
__global__ __launch_bounds__(256) void transpose_v_k(const unsigned short* __restrict__ V,
                                                     unsigned short* __restrict__ Vt) {
  const int bh = blockIdx.x;   // 32
  const int st = blockIdx.y;   // 32 s-tiles of 64
  const int tid = threadIdx.x;
  __shared__ unsigned short T[64 * 64];  // 8 KB
  const unsigned short* src = V + ((size_t)bh * 2048 + st * 64) * 64;  // contiguous 8KB

#pragma unroll
  for (int it = 0; it < 2; ++it) {
    const int c = it * 256 + tid;
    const int L = c * 16;
    const int S = L ^ (((L >> 10) & 7) << 4);
    gload_lds16((const char*)src + S, (char*)T + L);
  }
  __syncthreads();

#pragma unroll
  for (int it = 0; it < 2; ++it) {
    const int c = it * 256 + tid;
    const int d = c >> 3;
    const int s_off = (c & 7) * 8;
    const int xg = (c & 7) << 4;
    bf16x8 pk;
#pragma unroll
    for (int j = 0; j < 8; ++j)
      pk[j] = *(const short*)((const char*)T + (((s_off + j) * 128 + d * 2) ^ xg));
    *(bf16x8*)(Vt + (size_t)(bh * 64 + d) * VT_STRIDE + st * 64 + s_off) = pk;
  }
}

// C[M,N] = A[M,K](bf16) * W[N,K](bf16)^T + bias.
// MODE 0: Cout fp32 [M,N].  MODE 1: scatter to Q/K/V, all [bh, s, d] bf16 (coalesced).
// 128x128 tile, BK=64, 4 waves (2x2), 16x16x32 bf16 MFMA.
// 2-PHASE PIPELINE: double-buffered LDS staged via global_load_lds; per K-step
// {STAGE(next) -> s_waitcnt vmcnt(8) -> s_barrier -> MFMA -> s_barrier}.
// T2 XOR-swizzle via pre-swizzled global source.
template <int MODE, int N, int K>
__global__ __launch_bounds__(256) void gemm_bt(const unsigned short* __restrict__ A,
                                               const unsigned short* __restrict__ W,
                                               const float* __restrict__ bias,
                                               float* __restrict__ Cout,
                                               unsigned short* __restrict__ Qp,
                                               unsigned short* __restrict__ Kp,
                                               unsigned short* __restrict__ Vp) {
  __shared__ unsigned short As[2][128 * 64];
  __shared__ unsigned short Bs[2][128 * 64];
  const int tid = threadIdx.x;
  const int m0 = blockIdx.x * 128;
  const int n0 = blockIdx.y * 128;
  const int w = tid >> 6, lane = tid & 63, g = lane >> 4, lr = lane & 15;
  const int wr = w >> 1, wc = w & 1;
  const int xr = (lr & 7) << 4;

  f32x4 acc[4][4];
#pragma unroll
  for (int i = 0; i < 4; ++i)
#pragma unroll
    for (int j = 0; j < 4; ++j)
#pragma unroll
      for (int r = 0; r < 4; ++r) acc[i][j][r] = 0.f;

#define GSTAGE(buf, kt)                                                                     \
  do {                                                                                      \
    _Pragma("unroll")                                                                       \
    for (int it = 0; it < 4; ++it) {                                                        \
      const int c = it * 256 + tid;                                                         \
      const int row = c >> 3;                                                               \
      const int colb = ((c & 7) * 16) ^ ((row & 7) << 4);                                   \
      gload_lds16((const char*)(A + (size_t)(m0 + row) * K + (kt)) + colb,                  \
                  (char*)As[buf] + c * 16);                                                 \
      gload_lds16((const char*)(W + (size_t)(n0 + row) * K + (kt)) + colb,                  \
                  (char*)Bs[buf] + c * 16);                                                 \
    }                                                                                       \
  } while (0)

  GSTAGE(0, 0);
  int cur = 0;
  const int nsteps = K / 64;
  for (int step = 0; step < nsteps; ++step) {
    if (step + 1 < nsteps) {
      GSTAGE(cur ^ 1, (step + 1) * 64);
      asm volatile("s_waitcnt vmcnt(8)" ::: "memory");  // own tile loads landed; 8 newest in flight
    } else {
      asm volatile("s_waitcnt vmcnt(0)" ::: "memory");
    }
    __builtin_amdgcn_s_barrier();   // all waves' current-tile loads landed
    __builtin_amdgcn_sched_barrier(0);

    const char* AsC = (const char*)As[cur];
    const char* BsC = (const char*)Bs[cur];
    __builtin_amdgcn_s_setprio(1);
#pragma unroll
    for (int ks = 0; ks < 2; ++ks) {
      bf16x8 af[4], bf[4];
#pragma unroll
      for (int mi = 0; mi < 4; ++mi)
        af[mi] = *(const bf16x8*)(AsC +
                   ((((wr * 64 + mi * 16 + lr) * 128) + ks * 64 + g * 16) ^ xr));
#pragma unroll
      for (int ni = 0; ni < 4; ++ni)
        bf[ni] = *(const bf16x8*)(BsC +
                   ((((wc * 64 + ni * 16 + lr) * 128) + ks * 64 + g * 16) ^ xr));
#pragma unroll
      for (int mi = 0; mi < 4; ++mi)
#pragma unroll
        for (int ni = 0; ni < 4; ++ni)
          acc[mi][ni] = __builtin_amdgcn_mfma_f32_16x16x32_bf16(af[mi], bf[ni], acc[mi][ni], 0, 0, 0);
    }
    __builtin_amdgcn_s_setprio(0);

    asm volatile("" ::: "memory");
    __builtin_amdgcn_s_barrier();   // all waves done reading buf[cur]
    __builtin_amdgcn_sched_barrier(0);
    cur ^= 1;
  }
#undef GSTAGE

  if (MODE == 0) {
#pragma unroll
    for (int ni = 0; ni < 4; ++ni) {
      const int col = n0 + wc * 64 + ni * 16 + lr;
      const float bv = bias[col];
#pragma unroll
      for (int mi = 0; mi < 4; ++mi)
#pragma unroll
        for (int r = 0; r < 4; ++r) {
          const int row = m0 + wr * 64 + mi * 16 + g * 4 + r;
          Cout[(size_t)row * N + col] = acc[mi][ni][r] + bv;
        }
    }
  } else {
#pragma unroll
    for (int ni = 0; ni < 4; ++ni) {
      const int col = n0 + wc * 64 + ni * 16 + lr;
      const float bv = bias[col];
      const int which = col >> 10;
      const int h = (col >> 6) & 15;
      const int d = col & 63;
      unsigned short* P = which == 0 ? Qp : which == 1 ? Kp : Vp;
#pragma unroll
      for (int mi = 0; mi < 4; ++mi)
#pragma unroll
        for (int r = 0; r < 4; ++r) {
          const int row = m0 + wr * 64 + mi * 16 + g * 4 + r;
          const int b = row >> 11, s = row & 2047;
          P[(((size_t)(b * 16 + h) * 2048 + s) << 6) + d] = f2bf(acc[mi][ni][r] + bv);
        }
    }
  }
}

// Flash attention, causal. grid (bh=32, qb=8), 512 threads = 8 waves.
// Block processes TWO 128-row q-tiles: qt = qb and qt = 15-qb -> exactly 34
// kv-iterations per block (uniform makespan, 256 blocks = 1/CU, 8 waves/CU).
// Each wave owns 16 q-rows; staged K/V 64x64 tile pair feeds 128 q-rows
// (2x round-9 staging efficiency, half the barrier events per MFMA).
// K/V DOUBLE-BUFFERED in swizzled LDS via global_load_lds (2 loads/thread);
// counted s_waitcnt vmcnt(2). Swapped QK^T (mfma(K,Q)), cvt_pk P-pack,
// no-max exp2 softmax, per-lane l partials, one reduce per tile.
// Causal mask applies on the last TWO kv blocks of each tile (128-row tile
// spans two 64-key diagonal blocks; waves below the diagonal get thr<0 -> all
// masked, which is correct and costs one idle iter for half the waves).
__global__ __launch_bounds__(512) void attn_fwd(const unsigned short* __restrict__ Q,
                                                const unsigned short* __restrict__ Kg,
                                                const unsigned short* __restrict__ Vt,
                                                unsigned short* __restrict__ AO) {
  const int bh = blockIdx.x;            // b*16 + h
  const int qb = blockIdx.y;            // 0..7
  const int tid = threadIdx.x;
  const int w = tid >> 6, lane = tid & 63, g = lane >> 4, lr = lane & 15;
  const unsigned short* Qp = Q  + (size_t)bh * 2048 * 64;
  const unsigned short* Kp = Kg + (size_t)bh * 2048 * 64;
  const unsigned short* Vp = Vt + (size_t)bh * 64 * VT_STRIDE;
  const int b = bh >> 4, h = bh & 15;

  __shared__ unsigned short Ks[2][64 * 64];  // 16 KB dbuf K
  __shared__ unsigned short Vs[2][64 * 64];  // 16 KB dbuf V^T
  __shared__ unsigned short Pl[8][16 * 64];  // 16 KB per-wave P

  const float C = 0.1803368801f;  // 0.125 * log2(e)
  char* Plw = (char*)Pl[w];
  const int xr = (lr & 7) << 4;

  // staging: 512 threads x 16B cover one 8KB tile; thread's chunk L = tid*16
  const int L0 = tid * 16;
  const int G0 = L0 ^ (((L0 >> 7) & 7) << 4);

#define STAGE(buf, kvb)                                                                     \
  do {                                                                                      \
    gload_lds16((const char*)Kp + (size_t)(kvb) * 128 + G0, (char*)Ks[buf] + L0);           \
    gload_lds16((const char*)Vp + (size_t)(G0 >> 7) * (VT_STRIDE * 2) + (size_t)(kvb) * 2 + \
                    (G0 & 127), (char*)Vs[buf] + L0);                                       \
  } while (0)

#pragma unroll
  for (int half = 0; half < 2; ++half) {
    const int qt = half ? (15 - qb) : qb;
    const int nb = 2 * qt + 2;             // kv blocks of 64 cover rows < 128*qt+128
    const int qrow0 = qt * 128 + w * 16;   // this wave's 16 q-rows

    bf16x8 aq[2];
#pragma unroll
    for (int ks = 0; ks < 2; ++ks)
      aq[ks] = *(const bf16x8*)(Qp + (size_t)(qrow0 + lr) * 64 + ks * 32 + g * 8);

    f32x4 o[4];
    float lp = 0.f;  // partial row-sum for q = qrow0 + lr (this lane's keys only)
#pragma unroll
    for (int db = 0; db < 4; ++db)
#pragma unroll
      for (int r = 0; r < 4; ++r) o[db][r] = 0.f;

    STAGE(0, 0);
    int cur = 0;

    for (int t = 0; t < nb; ++t) {
      const int kvb = t * 64;
      if (t + 1 < nb) {
        STAGE(cur ^ 1, (t + 1) * 64);
        asm volatile("s_waitcnt vmcnt(2)" ::: "memory");  // own tile-t loads landed
      } else {
        asm volatile("s_waitcnt vmcnt(0)" ::: "memory");
      }
      __builtin_amdgcn_s_barrier();        // all waves' tile-t loads landed
      __builtin_amdgcn_sched_barrier(0);

      const char* KsC = (const char*)Ks[cur];
      const char* VsC = (const char*)Vs[cur];

      // ---- QK^T SWAPPED: D[col=q=lr, row=key=f*16+g*4+r] ----
      f32x4 sc[4];
#pragma unroll
      for (int f = 0; f < 4; ++f)
#pragma unroll
        for (int r = 0; r < 4; ++r) sc[f][r] = 0.f;
      __builtin_amdgcn_s_setprio(1);
#pragma unroll
      for (int ks = 0; ks < 2; ++ks)
#pragma unroll
        for (int f = 0; f < 4; ++f) {
          bf16x8 bk = *(const bf16x8*)(KsC + (((f * 16 + lr) * 128 + ks * 64 + g * 16) ^ xr));
          sc[f] = __builtin_amdgcn_mfma_f32_16x16x32_bf16(bk, aq[ks], sc[f], 0, 0, 0);
        }
      __builtin_amdgcn_s_setprio(0);

      // ---- causal mask: last TWO kv blocks may touch/cross the diagonal ----
      if (t >= nb - 2) {
        const int thr = qrow0 + lr - kvb - g * 4;
#pragma unroll
        for (int f = 0; f < 4; ++f)
#pragma unroll
          for (int r = 0; r < 4; ++r)
            if (f * 16 + r > thr) sc[f][r] = -INFINITY;
      }

      // ---- no-max softmax + per-lane partial sum ----
#pragma unroll
      for (int f = 0; f < 4; ++f) {
        float p0 = exp2f(sc[f][0] * C);
        float p1 = exp2f(sc[f][1] * C);
        float p2 = exp2f(sc[f][2] * C);
        float p3 = exp2f(sc[f][3] * C);
        sc[f][0] = p0; sc[f][1] = p1; sc[f][2] = p2; sc[f][3] = p3;
        lp += (p0 + p1) + (p2 + p3);
      }

      // ---- P -> LDS: keys g*4+0..3 adjacent -> cvt_pk pairs, one b64 per f ----
#pragma unroll
      for (int f = 0; f < 4; ++f) {
        unsigned w0, w1;
        asm("v_cvt_pk_bf16_f32 %0, %1, %2" : "=v"(w0) : "v"(sc[f][0]), "v"(sc[f][1]));
        asm("v_cvt_pk_bf16_f32 %0, %1, %2" : "=v"(w1) : "v"(sc[f][2]), "v"(sc[f][3]));
        uint2 pk; pk.x = w0; pk.y = w1;
        *(uint2*)(Plw + ((lr * 128 + f * 32 + g * 8) ^ xr)) = pk;
      }
      asm volatile("s_waitcnt lgkmcnt(0)" ::: "memory");
      __builtin_amdgcn_sched_barrier(0);

      // ---- PV: A = P[row=q=lr][k=keys], B = V^T[col=d][k=keys] ----
      __builtin_amdgcn_s_setprio(1);
#pragma unroll
      for (int ks = 0; ks < 2; ++ks) {
        bf16x8 pa = *(const bf16x8*)(Plw + ((lr * 128 + ks * 64 + g * 16) ^ xr));
#pragma unroll
        for (int db = 0; db < 4; ++db) {
          bf16x8 bv = *(const bf16x8*)(VsC + (((db * 16 + lr) * 128 + ks * 64 + g * 16) ^ xr));
          o[db] = __builtin_amdgcn_mfma_f32_16x16x32_bf16(pa, bv, o[db], 0, 0, 0);
        }
      }
      __builtin_amdgcn_s_setprio(0);

      asm volatile("" ::: "memory");
      __builtin_amdgcn_s_barrier();        // all waves done reading buf[cur]
      __builtin_amdgcn_sched_barrier(0);
      cur ^= 1;
    }

    // ---- finalize: reduce l across the 4 lane-groups, redistribute, output ----
    lp += __shfl_xor(lp, 16);
    lp += __shfl_xor(lp, 32);
    const float inv = 1.0f / lp;           // valid for q = qrow0 + lr on every lane
#pragma unroll
    for (int r = 0; r < 4; ++r) {
      const float linv = __shfl(inv, g * 4 + r);   // l for q-row g*4+r (o's row layout)
      const int row = qrow0 + g * 4 + r;
#pragma unroll
      for (int db = 0; db < 4; ++db)
        AO[(size_t)(b * 2048 + row) * 1024 + h * 64 + db * 16 + lr] = f2bf(o[db][r] * linv);
    }
  }
#undef STAGE
}

extern "C" void kernel_launch(void* const* d_in, const int* in_sizes, int n_in,
                              void* d_out, int out_size, void* d_ws, size_t ws_size,
                              hipStream_t stream) {
  const float* x     = (const float*)d_in[0];
  const float* W_qkv = (const float*)d_in[1];
  const float* b_qkv = (const float*)d_in[2];
  const float* W_out = (const float*)d_in[3];
  const float* b_out = (const float*)d_in[4];
  float* out = (float*)d_out;

  // workspace layout (48 MB exactly, fully rewritten every call)
  // AOb reuses xb's region: xb dead after QKV GEMM completes (stream-ordered).
  char* ws = (char*)d_ws;
  unsigned short* xb  = (unsigned short*)(ws);                      // 8 MB x bf16 [4096,1024]
  unsigned short* AOb = (unsigned short*)(ws);                      // 8 MB attn out (reuse)
  unsigned short* wqb = (unsigned short*)(ws + ((size_t)8 << 20));  // 6 MB W_qkv bf16
  unsigned short* wob = (unsigned short*)(ws + ((size_t)14 << 20)); // 2 MB W_out bf16
  unsigned short* Qb  = (unsigned short*)(ws + ((size_t)16 << 20)); // 8 MB Q [bh,s,d]
  unsigned short* Kb  = (unsigned short*)(ws + ((size_t)24 << 20)); // 8 MB K [bh,s,d]
  unsigned short* Vb  = (unsigned short*)(ws + ((size_t)32 << 20)); // 8 MB V [bh,s,d]
  unsigned short* Vtb = (unsigned short*)(ws + ((size_t)40 << 20)); // 8 MB V^T [bh,d,s]

  cvt_all_k<<<(N4_X + N4_WQ + N4_WO) / 256, 256, 0, stream>>>(x, W_qkv, W_out, xb, wqb, wob);

  gemm_bt<1, 3072, 1024><<<dim3(32, 24), 256, 0, stream>>>(xb, wqb, b_qkv, nullptr, Qb, Kb, Vb);
  transpose_v_k<<<dim3(32, 32), 256, 0, stream>>>(Vb, Vtb);
  attn_fwd<<<dim3(32, 8), 512, 0, stream>>>(Qb, Kb, Vtb, AOb);
  gemm_bt<0, 1024, 1024><<<dim3(32, 8), 256, 0, stream>>>(AOb, wob, b_out, out, nullptr, nullptr, nullptr);
}